// Round 2
// baseline (365.323 us; speedup 1.0000x reference)
//
#include <hip/hip_runtime.h>
#include <cmath>

// Izhikevich neuron step, N=8192.
// I = w@g + x_in  (256 MiB fp32 matvec read -> memory-bound, floor ~43us)
// then elementwise dynamics; outputs [v_out | spiked_s | u_out | g_out] flat.
//
// Layout: 1 wave per row, 4 rows per 256-thread block, 2048 blocks.
// g (32 KiB) staged to LDS once per block; w read as coalesced float4.

#define NN 8192
#define WAVES_PER_BLOCK 4
#define BLOCK (WAVES_PER_BLOCK * 64)

__global__ __launch_bounds__(BLOCK) void izh_kernel(
    const float* __restrict__ x_in,
    const float* __restrict__ v,
    const float* __restrict__ u,
    const float* __restrict__ g,
    const float* __restrict__ w,
    const float* __restrict__ a_p,
    const float* __restrict__ b_p,
    const float* __restrict__ c_p,
    const float* __restrict__ d_p,
    float* __restrict__ out)
{
    __shared__ float4 g_lds[NN / 4];  // 2048 float4 = 32 KiB

    const int tid = threadIdx.x;

    // Stage g into LDS: 2048 float4 / 256 threads = 8 each, coalesced.
    const float4* g4 = (const float4*)g;
    #pragma unroll
    for (int i = 0; i < (NN / 4) / BLOCK; ++i) {
        g_lds[tid + i * BLOCK] = g4[tid + i * BLOCK];
    }
    __syncthreads();

    const int wave = tid >> 6;
    const int lane = tid & 63;
    const int row  = blockIdx.x * WAVES_PER_BLOCK + wave;

    // Row dot product: 2048 float4 / 64 lanes = 32 float4 per lane.
    // 4 independent accumulators break the serial FMA dependence chain.
    const float4* w4 = (const float4*)(w + (size_t)row * NN);
    float acc0 = 0.0f, acc1 = 0.0f, acc2 = 0.0f, acc3 = 0.0f;
    #pragma unroll 8
    for (int k = 0; k < 32; ++k) {
        const int idx = lane + 64 * k;   // contiguous across wave: 1 KiB/instr
        float4 wv = w4[idx];
        float4 gv = g_lds[idx];
        acc0 = fmaf(wv.x, gv.x, acc0);
        acc1 = fmaf(wv.y, gv.y, acc1);
        acc2 = fmaf(wv.z, gv.z, acc2);
        acc3 = fmaf(wv.w, gv.w, acc3);
    }
    float acc = (acc0 + acc1) + (acc2 + acc3);

    // Wave-level reduction (wave = 64 lanes on gfx950).
    #pragma unroll
    for (int off = 32; off > 0; off >>= 1) {
        acc += __shfl_down(acc, off, 64);
    }

    if (lane == 0) {
        const float I  = acc + x_in[row];
        const float vv = v[row];
        const float uu = u[row];
        const float gg = g[row];

        const float v1 = vv + (0.04f * vv * vv + 5.0f * vv + 140.0f - uu + I);

        // differentiable spike surrogate
        const float s = 1.0f / (1.0f + expf(-4.0f * (v1 - 30.0f)));

        const float spiked = (v1 >= 30.0f) ? 1.0f : 0.0f;
        const float ns     = 1.0f - spiked;

        const float du = fabsf(a_p[row]) * (fabsf(b_p[row]) * v1 - uu);
        const float dg = -gg / 6.5f;

        out[0 * NN + row] = ns * v1 + spiked * c_p[row];        // v_out
        out[1 * NN + row] = s;                                  // spiked_s
        out[2 * NN + row] = ns * (uu + du) + spiked * d_p[row]; // u_out
        out[3 * NN + row] = ns * (gg + dg) + spiked;            // g_out
    }
}

extern "C" void kernel_launch(void* const* d_in, const int* in_sizes, int n_in,
                              void* d_out, int out_size, void* d_ws, size_t ws_size,
                              hipStream_t stream) {
    // setup_inputs() order: x_in, v, u, g, w, a_p, b_p, c_p, d_p
    const float* x_in = (const float*)d_in[0];
    const float* v    = (const float*)d_in[1];
    const float* u    = (const float*)d_in[2];
    const float* g    = (const float*)d_in[3];
    const float* w    = (const float*)d_in[4];
    const float* a_p  = (const float*)d_in[5];
    const float* b_p  = (const float*)d_in[6];
    const float* c_p  = (const float*)d_in[7];
    const float* d_p  = (const float*)d_in[8];
    float* out = (float*)d_out;

    const int grid = NN / WAVES_PER_BLOCK;  // 2048 blocks
    izh_kernel<<<grid, BLOCK, 0, stream>>>(x_in, v, u, g, w, a_p, b_p, c_p, d_p, out);
}

// Round 4
// 349.303 us; speedup vs baseline: 1.0459x; 1.0459x over previous
//
#include <hip/hip_runtime.h>
#include <cmath>

// Izhikevich neuron step, N=8192.
// I = w@g + x_in (256 MiB fp32 matvec, memory-bound, HBM floor ~43us)
// then elementwise dynamics; outputs [v_out | spiked_s | u_out | g_out].
//
// R3: same as R2 but nontemporal loads use a native clang ext_vector type
// (HIP float4 is a class -> rejected by __builtin_nontemporal_load).
// Layout: ONE 256-thread block per row (8192 blocks). Each lane owns
// 8 float4 of the row, fully unrolled -> all 8 global loads in flight.
// g (32 KiB) staged to LDS per block.

#define NN 8192
#define BLOCK 256

typedef float f4 __attribute__((ext_vector_type(4)));

__global__ __launch_bounds__(BLOCK) void izh_kernel(
    const float* __restrict__ x_in,
    const float* __restrict__ v,
    const float* __restrict__ u,
    const float* __restrict__ g,
    const float* __restrict__ w,
    const float* __restrict__ a_p,
    const float* __restrict__ b_p,
    const float* __restrict__ c_p,
    const float* __restrict__ d_p,
    float* __restrict__ out)
{
    __shared__ f4 g_lds[NN / 4];   // 32 KiB
    __shared__ float wave_part[BLOCK / 64];

    const int tid  = threadIdx.x;
    const int row  = blockIdx.x;
    const int lane = tid & 63;
    const int wave = tid >> 6;

    // Stage g into LDS: 2048 f4 / 256 threads = 8 each, coalesced.
    const f4* g4 = (const f4*)g;
    #pragma unroll
    for (int i = 0; i < (NN / 4) / BLOCK; ++i) {
        g_lds[tid + i * BLOCK] = g4[tid + i * BLOCK];
    }
    __syncthreads();

    // Row dot product: 2048 f4 / 256 threads = 8 f4 per lane.
    // Fully unrolled: all 8 nontemporal loads issue before any use.
    const f4* w4 = (const f4*)(w + (size_t)row * NN);
    f4 wv[8];
    #pragma unroll
    for (int k = 0; k < 8; ++k) {
        wv[k] = __builtin_nontemporal_load(&w4[tid + BLOCK * k]);
    }

    float acc0 = 0.0f, acc1 = 0.0f, acc2 = 0.0f, acc3 = 0.0f;
    #pragma unroll
    for (int k = 0; k < 8; ++k) {
        const f4 gv = g_lds[tid + BLOCK * k];
        acc0 = fmaf(wv[k].x, gv.x, acc0);
        acc1 = fmaf(wv[k].y, gv.y, acc1);
        acc2 = fmaf(wv[k].z, gv.z, acc2);
        acc3 = fmaf(wv[k].w, gv.w, acc3);
    }
    float acc = (acc0 + acc1) + (acc2 + acc3);

    // Wave reduction (64 lanes), then cross-wave via LDS.
    #pragma unroll
    for (int off = 32; off > 0; off >>= 1) {
        acc += __shfl_down(acc, off, 64);
    }
    if (lane == 0) wave_part[wave] = acc;
    __syncthreads();

    if (tid == 0) {
        const float dot = (wave_part[0] + wave_part[1])
                        + (wave_part[2] + wave_part[3]);

        const float I  = dot + x_in[row];
        const float vv = v[row];
        const float uu = u[row];
        const float gg = g[row];

        const float v1 = vv + (0.04f * vv * vv + 5.0f * vv + 140.0f - uu + I);

        // differentiable spike surrogate
        const float s = 1.0f / (1.0f + expf(-4.0f * (v1 - 30.0f)));

        const float spiked = (v1 >= 30.0f) ? 1.0f : 0.0f;
        const float ns     = 1.0f - spiked;

        const float du = fabsf(a_p[row]) * (fabsf(b_p[row]) * v1 - uu);
        const float dg = -gg / 6.5f;

        out[0 * NN + row] = ns * v1 + spiked * c_p[row];        // v_out
        out[1 * NN + row] = s;                                  // spiked_s
        out[2 * NN + row] = ns * (uu + du) + spiked * d_p[row]; // u_out
        out[3 * NN + row] = ns * (gg + dg) + spiked;            // g_out
    }
}

extern "C" void kernel_launch(void* const* d_in, const int* in_sizes, int n_in,
                              void* d_out, int out_size, void* d_ws, size_t ws_size,
                              hipStream_t stream) {
    // setup_inputs() order: x_in, v, u, g, w, a_p, b_p, c_p, d_p
    const float* x_in = (const float*)d_in[0];
    const float* v    = (const float*)d_in[1];
    const float* u    = (const float*)d_in[2];
    const float* g    = (const float*)d_in[3];
    const float* w    = (const float*)d_in[4];
    const float* a_p  = (const float*)d_in[5];
    const float* b_p  = (const float*)d_in[6];
    const float* c_p  = (const float*)d_in[7];
    const float* d_p  = (const float*)d_in[8];
    float* out = (float*)d_out;

    izh_kernel<<<NN, BLOCK, 0, stream>>>(x_in, v, u, g, w, a_p, b_p, c_p, d_p, out);
}